// Round 1
// baseline (799.350 us; speedup 1.0000x reference)
//
#include <hip/hip_runtime.h>

#define N_NODES 50000
#define N_EDGES 800000
#define NODE_F 256
#define EDGE_F 8
#define OUT_F 64

// ---------------------------------------------------------------------------
// Kernel 1: fused node GEMMs. blockIdx.y selects which projection:
//   0: fc   = feat @ W_src.T
//   1: asrc = feat @ W_attn_src.T
//   2: adst = feat @ W_attn_dst.T
//   3: res  = feat @ W_dst.T + b_dst
// Tile: 64 nodes x 64 outs per block, K-chunks of 32, 4x4 register tile.
// ---------------------------------------------------------------------------
__global__ __launch_bounds__(256) void node_gemm(
    const float* __restrict__ feat,
    const float* __restrict__ W_src,
    const float* __restrict__ W_attn_src,
    const float* __restrict__ W_attn_dst,
    const float* __restrict__ W_dst,
    const float* __restrict__ b_dst,
    float* __restrict__ fc, float* __restrict__ asrc,
    float* __restrict__ adst, float* __restrict__ res)
{
    const int sel = blockIdx.y;
    const float* __restrict__ W =
        sel == 0 ? W_src : sel == 1 ? W_attn_src : sel == 2 ? W_attn_dst : W_dst;
    float* __restrict__ out =
        sel == 0 ? fc : sel == 1 ? asrc : sel == 2 ? adst : res;

    __shared__ float A[64][33];   // [m][k] chunk
    __shared__ float B[64][33];   // [out][k] chunk

    const int tid = threadIdx.x;
    const int tx = tid & 15;      // -> 4 output cols
    const int ty = tid >> 4;      // -> 4 node rows
    const int m0 = blockIdx.x * 64;

    float acc[4][4] = {};

    for (int k0 = 0; k0 < NODE_F; k0 += 32) {
#pragma unroll
        for (int q = 0; q < 8; ++q) {
            int e = tid + q * 256;
            int ml = e >> 5, kl = e & 31;
            int m = m0 + ml;
            A[ml][kl] = (m < N_NODES) ? feat[(size_t)m * NODE_F + k0 + kl] : 0.f;
        }
#pragma unroll
        for (int q = 0; q < 8; ++q) {
            int e = tid + q * 256;
            int ol = e >> 5, kl = e & 31;
            B[ol][kl] = W[ol * NODE_F + k0 + kl];
        }
        __syncthreads();
#pragma unroll
        for (int kk = 0; kk < 32; ++kk) {
            float a[4], b[4];
#pragma unroll
            for (int i = 0; i < 4; ++i) a[i] = A[ty * 4 + i][kk];
#pragma unroll
            for (int j = 0; j < 4; ++j) b[j] = B[tx * 4 + j][kk];
#pragma unroll
            for (int i = 0; i < 4; ++i)
#pragma unroll
                for (int j = 0; j < 4; ++j) acc[i][j] += a[i] * b[j];
        }
        __syncthreads();
    }

#pragma unroll
    for (int i = 0; i < 4; ++i) {
        int m = m0 + ty * 4 + i;
        if (m >= N_NODES) continue;
        float4 v = make_float4(acc[i][0], acc[i][1], acc[i][2], acc[i][3]);
        if (sel == 3) {
            v.x += b_dst[tx * 4 + 0];
            v.y += b_dst[tx * 4 + 1];
            v.z += b_dst[tx * 4 + 2];
            v.w += b_dst[tx * 4 + 3];
        }
        *(float4*)&out[(size_t)m * OUT_F + tx * 4] = v;
    }
}

// ---------------------------------------------------------------------------
// Edge pass helper: recompute ex = exp(leaky_relu(asrc[s]+adst[d]+attn_edge))
// One 64-lane sub-wave per edge; lane = channel.
// ---------------------------------------------------------------------------
__device__ __forceinline__ float edge_ex(
    int eid, int c, int s, int d,
    const float* __restrict__ feat_edge,
    const float* __restrict__ W_ae,
    const float* __restrict__ asrc,
    const float* __restrict__ adst)
{
    float4 w0 = *(const float4*)&W_ae[c * EDGE_F];
    float4 w1 = *(const float4*)&W_ae[c * EDGE_F + 4];
    float4 f0 = *(const float4*)&feat_edge[(size_t)eid * EDGE_F];
    float4 f1 = *(const float4*)&feat_edge[(size_t)eid * EDGE_F + 4];
    float ae = w0.x * f0.x + w0.y * f0.y + w0.z * f0.z + w0.w * f0.w
             + w1.x * f1.x + w1.y * f1.y + w1.z * f1.z + w1.w * f1.w;
    float e = asrc[(size_t)s * OUT_F + c] + adst[(size_t)d * OUT_F + c] + ae;
    e = e > 0.f ? e : 0.2f * e;
    return __expf(e);
}

// Pass 1: accumulate softmax denominators for both segmentations.
__global__ __launch_bounds__(256) void edge_pass1(
    const float* __restrict__ feat_edge,
    const int* __restrict__ src_idx, const int* __restrict__ dst_idx,
    const float* __restrict__ W_ae,
    const float* __restrict__ asrc, const float* __restrict__ adst,
    float* __restrict__ s_dst, float* __restrict__ s_src)
{
    int t = blockIdx.x * 256 + threadIdx.x;
    int eid = t >> 6;
    int c = t & 63;
    if (eid >= N_EDGES) return;
    int s = src_idx[eid], d = dst_idx[eid];
    float ex = edge_ex(eid, c, s, d, feat_edge, W_ae, asrc, adst);
    atomicAdd(&s_dst[(size_t)d * OUT_F + c], ex);
    atomicAdd(&s_src[(size_t)s * OUT_F + c], ex);
}

// Pass 2: a = sqrt(clip(ex/s_dst)*clip(ex/s_src)); msg[dst] += fc[src]*a
__global__ __launch_bounds__(256) void edge_pass2(
    const float* __restrict__ feat_edge,
    const int* __restrict__ src_idx, const int* __restrict__ dst_idx,
    const float* __restrict__ W_ae,
    const float* __restrict__ asrc, const float* __restrict__ adst,
    const float* __restrict__ s_dst, const float* __restrict__ s_src,
    const float* __restrict__ fc, float* __restrict__ msg)
{
    int t = blockIdx.x * 256 + threadIdx.x;
    int eid = t >> 6;
    int c = t & 63;
    if (eid >= N_EDGES) return;
    int s = src_idx[eid], d = dst_idx[eid];
    float ex = edge_ex(eid, c, s, d, feat_edge, W_ae, asrc, adst);
    float sd = s_dst[(size_t)d * OUT_F + c];
    float ss = s_src[(size_t)s * OUT_F + c];
    float a_d = fmaxf(ex / sd, 1e-9f);
    float a_s = fmaxf(ex / ss, 1e-9f);
    float a = sqrtf(a_d * a_s);
    atomicAdd(&msg[(size_t)d * OUT_F + c], fc[(size_t)s * OUT_F + c] * a);
}

// ---------------------------------------------------------------------------
// Kernel 4: per-node layernorm over 64 channels, h @ W_agg.T + b_agg + res.
// One 64-lane wave per node, 4 nodes per block (50000 = 4 * 12500, exact).
// ---------------------------------------------------------------------------
__global__ __launch_bounds__(256) void post_kernel(
    const float* __restrict__ msg,
    const float* __restrict__ scale, const float* __restrict__ offset,
    const float* __restrict__ W_agg, const float* __restrict__ b_agg,
    const float* __restrict__ res, float* __restrict__ out)
{
    __shared__ float hbuf[4][OUT_F];
    int t = blockIdx.x * 256 + threadIdx.x;
    int n = t >> 6;
    int c = t & 63;
    int ln = threadIdx.x >> 6;

    float x = msg[(size_t)n * OUT_F + c];
    float s1 = x, s2 = x * x;
#pragma unroll
    for (int off = 32; off; off >>= 1) {
        s1 += __shfl_xor(s1, off, 64);
        s2 += __shfl_xor(s2, off, 64);
    }
    float mean = s1 * (1.f / OUT_F);
    float var = s2 * (1.f / OUT_F) - mean * mean + 1e-9f;
    float h = (x - mean) * scale[c] * rsqrtf(var) + offset[c];
    hbuf[ln][c] = h;
    __syncthreads();

    float acc = 0.f;
#pragma unroll
    for (int j = 0; j < OUT_F; j += 4) {
        float4 w = *(const float4*)&W_agg[c * OUT_F + j];
        acc += w.x * hbuf[ln][j] + w.y * hbuf[ln][j + 1]
             + w.z * hbuf[ln][j + 2] + w.w * hbuf[ln][j + 3];
    }
    out[(size_t)n * OUT_F + c] = acc + b_agg[c] + res[(size_t)n * OUT_F + c];
}

// ---------------------------------------------------------------------------
extern "C" void kernel_launch(void* const* d_in, const int* in_sizes, int n_in,
                              void* d_out, int out_size, void* d_ws, size_t ws_size,
                              hipStream_t stream) {
    const float* feat_src    = (const float*)d_in[0];
    const float* feat_edge   = (const float*)d_in[1];
    const int*   src_idx     = (const int*)d_in[2];
    const int*   dst_idx     = (const int*)d_in[3];
    const float* W_src       = (const float*)d_in[4];
    const float* W_dst       = (const float*)d_in[5];
    const float* b_dst       = (const float*)d_in[6];
    const float* W_attn_src  = (const float*)d_in[7];
    const float* W_attn_dst  = (const float*)d_in[8];
    const float* W_attn_edge = (const float*)d_in[9];
    const float* scale       = (const float*)d_in[10];
    const float* offset      = (const float*)d_in[11];
    const float* W_agg       = (const float*)d_in[12];
    const float* b_agg       = (const float*)d_in[13];
    float* out = (float*)d_out;

    const size_t NF = (size_t)N_NODES * OUT_F;
    float* ws    = (float*)d_ws;
    float* fc    = ws;             // [N,64]
    float* asrc  = fc + NF;        // [N,64]
    float* adst  = asrc + NF;      // [N,64]
    float* res   = adst + NF;      // [N,64]
    float* s_dst = res + NF;       // [N,64]
    float* s_src = s_dst + NF;     // [N,64]
    float* msg   = s_src + NF;     // [N,64]

    // zero the three accumulator arrays (contiguous)
    hipMemsetAsync(s_dst, 0, 3 * NF * sizeof(float), stream);

    dim3 g1((N_NODES + 63) / 64, 4);
    node_gemm<<<g1, 256, 0, stream>>>(feat_src, W_src, W_attn_src, W_attn_dst,
                                      W_dst, b_dst, fc, asrc, adst, res);

    const int eblocks = (N_EDGES * OUT_F) / 256;  // 200000
    edge_pass1<<<eblocks, 256, 0, stream>>>(feat_edge, src_idx, dst_idx,
                                            W_attn_edge, asrc, adst, s_dst, s_src);
    edge_pass2<<<eblocks, 256, 0, stream>>>(feat_edge, src_idx, dst_idx,
                                            W_attn_edge, asrc, adst, s_dst, s_src,
                                            fc, msg);

    post_kernel<<<N_NODES / 4, 256, 0, stream>>>(msg, scale, offset, W_agg,
                                                 b_agg, res, out);
}